// Round 1
// baseline (18.466 us; speedup 1.0000x reference)
//
#include <hip/hip_runtime.h>

// Fused quantum-transformer block for MI355X.
//
// Closed-form circuit: OPS = ry(0,t0) rx(3,t1) rz(5,t2) cx(1,4) ry(6,t3)
// rx(2,t4) cx(0,7) rz(4,t5) on RX(a_w)-encoded product state.
// Z-expectations (t2,t5 drop out; CNOT maps Z_target -> Z_c Z_t):
//   z0 = cos(t0) cos(a0)
//   z1 = cos(a1)
//   z2 = cos(a2 + t4)
//   z3 = cos(a3 + t1)
//   z4 = cos(a1) cos(a4)
//   z5 = cos(a5)
//   z6 = cos(t3) cos(a6)
//   z7 = cos(t0) cos(a0) cos(a7)

__device__ __forceinline__ float wave_sum(float v) {
#pragma unroll
    for (int m = 32; m > 0; m >>= 1) v += __shfl_xor(v, m, 64);
    return v;
}

__global__ __launch_bounds__(256, 1)
void qtb_fused(const float* __restrict__ x,
               const float* __restrict__ attn_theta,
               const float* __restrict__ Wc,
               const float* __restrict__ bc,
               const float* __restrict__ g1,
               const float* __restrict__ beta1,
               const float* __restrict__ ffn_theta,
               const float* __restrict__ W1,
               const float* __restrict__ b1,
               const float* __restrict__ W2,
               const float* __restrict__ b2,
               const float* __restrict__ g2,
               const float* __restrict__ beta2,
               float* __restrict__ out)
{
    __shared__ __align__(16) float sWc[64 * 64];     // 16 KB
    __shared__ __align__(16) float sW1[8 * 256];     //  8 KB
    __shared__ __align__(16) float sW2[256 * 64];    // 64 KB
    __shared__ __align__(16) float sZ[4][4][64];     //  4 KB
    __shared__ __align__(16) float sH[4][4][256];    // 16 KB

    const int tid  = threadIdx.x;
    const int lane = tid & 63;
    const int wv   = tid >> 6;       // wave id 0..3
    const int w    = lane & 7;       // qubit index within 8-group
    const int gb   = lane & ~7;      // group base lane

    // ---- stage weights to LDS (float4) ----
    {
        const float4* s;
        float4* d;
        s = (const float4*)Wc;  d = (float4*)sWc;
#pragma unroll
        for (int i = 0; i < 4; ++i)  d[tid + 256 * i] = s[tid + 256 * i];
        s = (const float4*)W1;  d = (float4*)sW1;
#pragma unroll
        for (int i = 0; i < 2; ++i)  d[tid + 256 * i] = s[tid + 256 * i];
        s = (const float4*)W2;  d = (float4*)sW2;
#pragma unroll
        for (int i = 0; i < 16; ++i) d[tid + 256 * i] = s[tid + 256 * i];
    }

    // thetas (t2, t5 provably don't affect Z expectations)
    const float C0a = cosf(attn_theta[0]);
    const float T1a = attn_theta[1];
    const float C3a = cosf(attn_theta[3]);
    const float T4a = attn_theta[4];
    const float C0f = cosf(ffn_theta[0]);
    const float T1f = ffn_theta[1];
    const float C3f = cosf(ffn_theta[3]);
    const float T4f = ffn_theta[4];

    // per-lane parameters (constant across tokens)
    const float bcL  = bc[lane];
    const float g1L  = g1[lane];
    const float be1L = beta1[lane];
    const float b2L  = b2[lane];
    const float g2L  = g2[lane];
    const float be2L = beta2[lane];
    float b1L[4];
#pragma unroll
    for (int r = 0; r < 4; ++r) b1L[r] = b1[r * 64 + lane];

    const int tok0 = (blockIdx.x * 4 + wv) * 4;   // 4 tokens per wave

    float xr[4];
#pragma unroll
    for (int t = 0; t < 4; ++t) xr[t] = x[(tok0 + t) * 64 + lane];

    // ---- quantum attention expectations (closed form) ----
    const float dA = (w == 2) ? T4a : ((w == 3) ? T1a : 0.0f);
#pragma unroll
    for (int t = 0; t < 4; ++t) {
        float c  = cosf(xr[t] + dA);
        float c0 = __shfl(c, gb, 64);        // cos(a0) of this 8-group
        float c1 = __shfl(c, gb + 1, 64);    // cos(a1)
        float mm = (w == 0) ? C0a : ((w == 6) ? C3a : 1.0f);
        float z  = c * mm;
        if (w == 4) z = c * c1;
        if (w == 7) z = C0a * c0 * c;
        sZ[wv][t][lane] = z;
    }
    __syncthreads();

    // ---- attn = Z @ Wc + bc (each lane = one output column) ----
    float acc[4];
#pragma unroll
    for (int t = 0; t < 4; ++t) acc[t] = bcL;
#pragma unroll 4
    for (int q = 0; q < 16; ++q) {
        float w0 = sWc[(4 * q + 0) * 64 + lane];
        float w1 = sWc[(4 * q + 1) * 64 + lane];
        float w2 = sWc[(4 * q + 2) * 64 + lane];
        float w3 = sWc[(4 * q + 3) * 64 + lane];
#pragma unroll
        for (int t = 0; t < 4; ++t) {
            float4 zv = *(const float4*)&sZ[wv][t][4 * q];  // broadcast read
            acc[t] = fmaf(zv.x, w0, acc[t]);
            acc[t] = fmaf(zv.y, w1, acc[t]);
            acc[t] = fmaf(zv.z, w2, acc[t]);
            acc[t] = fmaf(zv.w, w3, acc[t]);
        }
    }

    // ---- y = LN(x + attn) ----
    float y[4];
#pragma unroll
    for (int t = 0; t < 4; ++t) {
        float v   = xr[t] + acc[t];
        float m   = wave_sum(v) * (1.0f / 64.0f);
        float d   = v - m;
        float var = wave_sum(d * d) * (1.0f / 64.0f);
        y[t] = d * rsqrtf(var + 1e-5f) * g1L + be1L;
    }

    // ---- ffn quantum gate + h = relu(QF @ W1 + b1) -> LDS ----
    const float dF = (w == 2) ? T4f : ((w == 3) ? T1f : 0.0f);
#pragma unroll
    for (int t = 0; t < 4; ++t) {
        float cy = cosf(y[t] + dF);          // meaningful on lanes 0..7
        float c0 = __shfl(cy, 0, 64);
        float c1 = __shfl(cy, 1, 64);
        float mm = (w == 0) ? C0f : ((w == 6) ? C3f : 1.0f);
        float qz = cy * mm;
        if (w == 4) qz = cy * c1;
        if (w == 7) qz = C0f * c0 * cy;
        float qk[8];
#pragma unroll
        for (int k = 0; k < 8; ++k) qk[k] = __shfl(qz, k, 64);
#pragma unroll
        for (int r = 0; r < 4; ++r) {
            float a = b1L[r];
#pragma unroll
            for (int k = 0; k < 8; ++k)
                a = fmaf(qk[k], sW1[k * 256 + r * 64 + lane], a);
            sH[wv][t][r * 64 + lane] = fmaxf(a, 0.0f);
        }
    }
    __syncthreads();

    // ---- ffn = H @ W2 + b2 ----
    float acc2[4];
#pragma unroll
    for (int t = 0; t < 4; ++t) acc2[t] = b2L;
#pragma unroll 2
    for (int q = 0; q < 64; ++q) {
        float w0 = sW2[(4 * q + 0) * 64 + lane];
        float w1 = sW2[(4 * q + 1) * 64 + lane];
        float w2 = sW2[(4 * q + 2) * 64 + lane];
        float w3 = sW2[(4 * q + 3) * 64 + lane];
#pragma unroll
        for (int t = 0; t < 4; ++t) {
            float4 hv = *(const float4*)&sH[wv][t][4 * q];  // broadcast read
            acc2[t] = fmaf(hv.x, w0, acc2[t]);
            acc2[t] = fmaf(hv.y, w1, acc2[t]);
            acc2[t] = fmaf(hv.z, w2, acc2[t]);
            acc2[t] = fmaf(hv.w, w3, acc2[t]);
        }
    }

    // ---- out = LN(y + ffn) ----
#pragma unroll
    for (int t = 0; t < 4; ++t) {
        float v   = y[t] + acc2[t];
        float m   = wave_sum(v) * (1.0f / 64.0f);
        float d   = v - m;
        float var = wave_sum(d * d) * (1.0f / 64.0f);
        out[(tok0 + t) * 64 + lane] = d * rsqrtf(var + 1e-5f) * g2L + be2L;
    }
}

extern "C" void kernel_launch(void* const* d_in, const int* in_sizes, int n_in,
                              void* d_out, int out_size, void* d_ws, size_t ws_size,
                              hipStream_t stream)
{
    const float* x   = (const float*)d_in[0];
    const float* at  = (const float*)d_in[1];
    const float* Wc  = (const float*)d_in[2];
    const float* bcp = (const float*)d_in[3];
    const float* g1  = (const float*)d_in[4];
    const float* be1 = (const float*)d_in[5];
    const float* ft  = (const float*)d_in[6];
    const float* W1  = (const float*)d_in[7];
    const float* b1  = (const float*)d_in[8];
    const float* W2  = (const float*)d_in[9];
    const float* b2  = (const float*)d_in[10];
    const float* g2  = (const float*)d_in[11];
    const float* be2 = (const float*)d_in[12];
    float* out = (float*)d_out;

    // 4096 tokens = 256 blocks x 4 waves x 4 tokens
    qtb_fused<<<256, 256, 0, stream>>>(x, at, Wc, bcp, g1, be1, ft,
                                       W1, b1, W2, b2, g2, be2, out);
}

// Round 3
// 16.771 us; speedup vs baseline: 1.1010x; 1.1010x over previous
//
#include <hip/hip_runtime.h>

// Fused quantum-transformer block, v3: zero-LDS, zero-barrier, readlane-broadcast.
// (v2 with the cvt_pkrtz/fdot2 vector-type mismatch fixed via int bit_casts.)
//
// Closed-form circuit (verified round 1): OPS = ry(0,t0) rx(3,t1) rz(5,t2)
// cx(1,4) ry(6,t3) rx(2,t4) cx(0,7) rz(4,t5) on RX(a_w)-encoded product state.
//   z0 = cos(t0) cos(a0)          z4 = cos(a1) cos(a4)
//   z1 = cos(a1)                  z5 = cos(a5)
//   z2 = cos(a2 + t4)             z6 = cos(t3) cos(a6)
//   z3 = cos(a3 + t1)             z7 = cos(t0) cos(a0) cos(a7)
//
// Mapping: lane = embedding index e (64 lanes), each wave owns 4 tokens.

#define USE_DOT2 (__has_builtin(__builtin_amdgcn_fdot2) && __has_builtin(__builtin_amdgcn_cvt_pkrtz))

#if USE_DOT2
typedef _Float16 h2f __attribute__((ext_vector_type(2)));   // what fdot2 takes
// cvt_pkrtz natively returns a __fp16 vector; go through int to avoid any
// implicit vector conversions.
__device__ __forceinline__ int pk(float a, float b) {
    return __builtin_bit_cast(int, __builtin_amdgcn_cvt_pkrtz(a, b));
}
__device__ __forceinline__ float fdot2i(int a, int b, float c) {
    return __builtin_amdgcn_fdot2(__builtin_bit_cast(h2f, a),
                                  __builtin_bit_cast(h2f, b), c, false);
}
#endif

__device__ __forceinline__ float rl_f(float v, int l) {
    return __int_as_float(__builtin_amdgcn_readlane(__float_as_int(v), l));
}

__device__ __forceinline__ void wave_sum2(float& a, float& b) {
#pragma unroll
    for (int m = 32; m > 0; m >>= 1) {
        a += __shfl_xor(a, m, 64);
        b += __shfl_xor(b, m, 64);
    }
}

__global__ __launch_bounds__(256)
void qtb_fused3(const float* __restrict__ x,
                const float* __restrict__ th_a,
                const float* __restrict__ Wc,
                const float* __restrict__ bc,
                const float* __restrict__ g1,
                const float* __restrict__ be1,
                const float* __restrict__ th_f,
                const float* __restrict__ W1,
                const float* __restrict__ b1,
                const float* __restrict__ W2,
                const float* __restrict__ b2,
                const float* __restrict__ g2,
                const float* __restrict__ be2,
                float* __restrict__ out)
{
    const int lane = threadIdx.x & 63;
    const int wv   = threadIdx.x >> 6;
    const int w    = lane & 7;
    const int gb   = lane & ~7;
    const int tok0 = (blockIdx.x * 4 + wv) * 4;   // 4 tokens per wave

    // thetas (t2, t5 are RZ — cannot affect <Z>)
    const float C0a = __cosf(th_a[0]);
    const float T1a = th_a[1];
    const float C3a = __cosf(th_a[3]);
    const float T4a = th_a[4];
    const float C0f = __cosf(th_f[0]);
    const float T1f = th_f[1];
    const float C3f = __cosf(th_f[3]);
    const float T4f = th_f[4];

    const float bcL = bc[lane], g1L = g1[lane], be1L = be1[lane];
    const float b2L = b2[lane], g2L = g2[lane], be2L = be2[lane];
    float b1L[4];
#pragma unroll
    for (int r = 0; r < 4; ++r) b1L[r] = b1[r * 64 + lane];

    float xr[4], z[4];
#pragma unroll
    for (int t = 0; t < 4; ++t) xr[t] = x[(tok0 + t) * 64 + lane];

    // ---- quantum attention expectations (closed form, in registers) ----
    const float dA = (w == 2) ? T4a : ((w == 3) ? T1a : 0.0f);
#pragma unroll
    for (int t = 0; t < 4; ++t) {
        float c  = __cosf(xr[t] + dA);
        float c0 = __shfl(c, gb, 64);       // cos(a0) of this 8-group
        float c1 = __shfl(c, gb + 1, 64);   // cos(a1)
        float zz = c * ((w == 0) ? C0a : ((w == 6) ? C3a : 1.0f));
        if (w == 4) zz = c * c1;
        if (w == 7) zz = C0a * c0 * c;
        z[t] = zz;
    }

    // ---- attn = Z @ Wc + bc : readlane-broadcast GEMV (K=64) ----
    float acc[4];
#pragma unroll
    for (int t = 0; t < 4; ++t) acc[t] = bcL;
#pragma unroll 8
    for (int q = 0; q < 64; ++q) {
        float wq = Wc[q * 64 + lane];        // coalesced, L1/L2-resident
#pragma unroll
        for (int t = 0; t < 4; ++t)
            acc[t] = fmaf(rl_f(z[t], q), wq, acc[t]);
    }

    // ---- y = LN(x + attn) (fused mean/var, one butterfly pass) ----
    float y[4];
#pragma unroll
    for (int t = 0; t < 4; ++t) {
        float v = xr[t] + acc[t];
        float s = v, s2 = v * v;
        wave_sum2(s, s2);
        float m   = s * 0.015625f;
        float var = s2 * 0.015625f - m * m;
        y[t] = (v - m) * rsqrtf(var + 1e-5f) * g1L + be1L;
    }

    // ---- ffn quantum gate (on y[:,:8]) + h = relu(QF @ W1 + b1) in regs ----
    float w1r[4][8];
#pragma unroll
    for (int k = 0; k < 8; ++k)
#pragma unroll
        for (int r = 0; r < 4; ++r) w1r[r][k] = W1[k * 256 + r * 64 + lane];

    const float dF = (w == 2) ? T4f : ((w == 3) ? T1f : 0.0f);
    float h[4][4];
#pragma unroll
    for (int t = 0; t < 4; ++t) {
        float cy = __cosf(y[t] + dF);        // meaningful on lanes 0..7
        float c0 = rl_f(cy, 0);
        float c1 = rl_f(cy, 1);
        float qz = cy * ((w == 0) ? C0f : ((w == 6) ? C3f : 1.0f));
        if (w == 4) qz = cy * c1;
        if (w == 7) qz = C0f * c0 * cy;
        float qf[8];
#pragma unroll
        for (int k = 0; k < 8; ++k) qf[k] = rl_f(qz, k);
#pragma unroll
        for (int r = 0; r < 4; ++r) {
            float a = b1L[r];
#pragma unroll
            for (int k = 0; k < 8; ++k) a = fmaf(qf[k], w1r[r][k], a);
            h[t][r] = fmaxf(a, 0.0f);
        }
    }

    // ---- ffn2 = H @ W2 + b2 (K=256), pairs (j, j+64) via v_dot2_f32_f16 ----
    float a2[4];
#pragma unroll
    for (int t = 0; t < 4; ++t) a2[t] = b2L;

#if USE_DOT2
    int hp[4][2];
#pragma unroll
    for (int t = 0; t < 4; ++t) {
        hp[t][0] = pk(h[t][0], h[t][1]);   // (h[kk], h[kk+64]) when readlane'd at kk
        hp[t][1] = pk(h[t][2], h[t][3]);   // (h[kk+128], h[kk+192])
    }
#pragma unroll 4
    for (int kk = 0; kk < 64; ++kk) {
        float wa = W2[(kk      ) * 64 + lane];
        float wb = W2[(kk +  64) * 64 + lane];
        float wc = W2[(kk + 128) * 64 + lane];
        float wd = W2[(kk + 192) * 64 + lane];
        int wp0 = pk(wa, wb);
        int wp1 = pk(wc, wd);
#pragma unroll
        for (int t = 0; t < 4; ++t) {
            a2[t] = fdot2i(__builtin_amdgcn_readlane(hp[t][0], kk), wp0, a2[t]);
            a2[t] = fdot2i(__builtin_amdgcn_readlane(hp[t][1], kk), wp1, a2[t]);
        }
    }
#else
#pragma unroll 4
    for (int kk = 0; kk < 64; ++kk) {
        float wa = W2[(kk      ) * 64 + lane];
        float wb = W2[(kk +  64) * 64 + lane];
        float wc = W2[(kk + 128) * 64 + lane];
        float wd = W2[(kk + 192) * 64 + lane];
#pragma unroll
        for (int t = 0; t < 4; ++t) {
            a2[t] = fmaf(rl_f(h[t][0], kk), wa, a2[t]);
            a2[t] = fmaf(rl_f(h[t][1], kk), wb, a2[t]);
            a2[t] = fmaf(rl_f(h[t][2], kk), wc, a2[t]);
            a2[t] = fmaf(rl_f(h[t][3], kk), wd, a2[t]);
        }
    }
#endif

    // ---- out = LN(y + ffn) ----
#pragma unroll
    for (int t = 0; t < 4; ++t) {
        float v = y[t] + a2[t];
        float s = v, s2 = v * v;
        wave_sum2(s, s2);
        float m   = s * 0.015625f;
        float var = s2 * 0.015625f - m * m;
        out[(tok0 + t) * 64 + lane] = (v - m) * rsqrtf(var + 1e-5f) * g2L + be2L;
    }
}

extern "C" void kernel_launch(void* const* d_in, const int* in_sizes, int n_in,
                              void* d_out, int out_size, void* d_ws, size_t ws_size,
                              hipStream_t stream)
{
    const float* x   = (const float*)d_in[0];
    const float* at  = (const float*)d_in[1];
    const float* Wc  = (const float*)d_in[2];
    const float* bcp = (const float*)d_in[3];
    const float* g1  = (const float*)d_in[4];
    const float* be1 = (const float*)d_in[5];
    const float* ft  = (const float*)d_in[6];
    const float* W1  = (const float*)d_in[7];
    const float* b1  = (const float*)d_in[8];
    const float* W2  = (const float*)d_in[9];
    const float* b2  = (const float*)d_in[10];
    const float* g2  = (const float*)d_in[11];
    const float* be2 = (const float*)d_in[12];
    float* out = (float*)d_out;

    // 4096 tokens = 256 blocks x 4 waves x 4 tokens (no LDS, no barriers)
    qtb_fused3<<<256, 256, 0, stream>>>(x, at, Wc, bcp, g1, be1, ft,
                                        W1, b1, W2, b2, g2, be2, out);
}